// Round 3
// baseline (23.766 us; speedup 1.0000x reference)
//
#include <hip/hip_runtime.h>

// out[b,i,j,c] = sum_d tanh(start[b,c,i,d] + end[b,c,j,d]) * v[d]
// B=2, C=8, L=256, D=128.
//
// tanh(x) = 1 - 2/(e^{2x}+1);  e^{2(s+e)} = Es*Ee, Es=exp2(K*s), K=2*log2(e).
// Inner loop per d-quad merges ALL 4 divisions into one rcp:
//   sum v_d/a_d = (n01*cd + n23*ab) / (ab*cd),  a_d = fma(Es,Ee,1) in (1, e^20]
// -> 14 full-rate VALU + 1 rcp per 4 elements.
// out = sum(v) - 2 * sum_d v_d/a_d.
// 64x64 tile, 4x4 register blocking -> 2 B LDS traffic per element.

#define LDIM 256
#define DDIM 128
#define DPAD 132   // 528 B rows: 16B-aligned, strided rows -> 2-way (free)

__global__ __launch_bounds__(256) void span_tanh_dot_kernel(
    const float* __restrict__ start_h,
    const float* __restrict__ end_h,
    const float* __restrict__ v,
    float* __restrict__ out,
    int C)
{
    __shared__ float s_t[64][DPAD];
    __shared__ float e_t[64][DPAD];
    __shared__ float s_vsum;

    const int bc = blockIdx.z;            // b*C + c
    const int i0 = blockIdx.y * 64;
    const int j0 = blockIdx.x * 64;
    const int tx = threadIdx.x;           // 0..15
    const int ty = threadIdx.y;           // 0..15
    const int tid = ty * 16 + tx;

    const float K = 2.8853900817779268f;  // 2*log2(e)

    const float* sg = start_h + ((size_t)bc * LDIM + i0) * DDIM;
    const float* eg = end_h   + ((size_t)bc * LDIM + j0) * DDIM;

    // stage 64x128 tiles of Es, Ee: 2048 float4 per tensor, 8 per thread.
    #pragma unroll
    for (int k = 0; k < 8; ++k) {
        const int idx = tid + k * 256;
        const int r  = idx >> 5;
        const int c4 = (idx & 31) << 2;
        float4 a = *(const float4*)(sg + r * DDIM + c4);
        a.x = __builtin_amdgcn_exp2f(K * a.x);
        a.y = __builtin_amdgcn_exp2f(K * a.y);
        a.z = __builtin_amdgcn_exp2f(K * a.z);
        a.w = __builtin_amdgcn_exp2f(K * a.w);
        *(float4*)(&s_t[r][c4]) = a;
        float4 b = *(const float4*)(eg + r * DDIM + c4);
        b.x = __builtin_amdgcn_exp2f(K * b.x);
        b.y = __builtin_amdgcn_exp2f(K * b.y);
        b.z = __builtin_amdgcn_exp2f(K * b.z);
        b.w = __builtin_amdgcn_exp2f(K * b.w);
        *(float4*)(&e_t[r][c4]) = b;
    }

    // sum(v): wave 0 reduces 128 floats
    if (tid < 64) {
        float2 vv = *(const float2*)(v + 2 * tid);
        float p = vv.x + vv.y;
        #pragma unroll
        for (int off = 32; off > 0; off >>= 1) p += __shfl_down(p, off);
        if (tid == 0) s_vsum = p;
    }
    __syncthreads();

    float acc[4][4];
    #pragma unroll
    for (int a = 0; a < 4; ++a)
        #pragma unroll
        for (int b = 0; b < 4; ++b) acc[a][b] = 0.0f;

    #pragma unroll 4
    for (int d = 0; d < DDIM; d += 4) {
        float4 S[4], E[4];
        S[0] = *(const float4*)(&s_t[ty     ][d]);   // broadcast across tx
        S[1] = *(const float4*)(&s_t[ty + 16][d]);
        S[2] = *(const float4*)(&s_t[ty + 32][d]);
        S[3] = *(const float4*)(&s_t[ty + 48][d]);
        E[0] = *(const float4*)(&e_t[tx     ][d]);   // strided rows: 2-way max
        E[1] = *(const float4*)(&e_t[tx + 16][d]);
        E[2] = *(const float4*)(&e_t[tx + 32][d]);
        E[3] = *(const float4*)(&e_t[tx + 48][d]);
        const float v0 = v[d], v1 = v[d + 1], v2 = v[d + 2], v3 = v[d + 3];

        #pragma unroll
        for (int a = 0; a < 4; ++a) {
            #pragma unroll
            for (int b = 0; b < 4; ++b) {
                float qa = fmaf(S[a].x, E[b].x, 1.0f);
                float qb = fmaf(S[a].y, E[b].y, 1.0f);
                float qc = fmaf(S[a].z, E[b].z, 1.0f);
                float qd = fmaf(S[a].w, E[b].w, 1.0f);
                float ab = qa * qb, cd = qc * qd;
                float n01 = fmaf(v0, qb, v1 * qa);   // v0/qa + v1/qb, over ab
                float n23 = fmaf(v2, qd, v3 * qc);
                float N = fmaf(n01, cd, n23 * ab);
                float r = __builtin_amdgcn_rcpf(ab * cd);
                acc[a][b] = fmaf(N, r, acc[a][b]);
            }
        }
    }

    const int b_ = bc / C;
    const int c_ = bc - b_ * C;
    const float Sv = s_vsum;
    #pragma unroll
    for (int a = 0; a < 4; ++a) {
        const int i = i0 + ty + 16 * a;
        #pragma unroll
        for (int b2 = 0; b2 < 4; ++b2) {
            const int j = j0 + tx + 16 * b2;
            out[(((size_t)b_ * LDIM + i) * LDIM + j) * C + c_] =
                fmaf(-2.0f, acc[a][b2], Sv);
        }
    }
}

extern "C" void kernel_launch(void* const* d_in, const int* in_sizes, int n_in,
                              void* d_out, int out_size, void* d_ws, size_t ws_size,
                              hipStream_t stream) {
    const float* start_h = (const float*)d_in[0];
    const float* end_h   = (const float*)d_in[1];
    const float* v       = (const float*)d_in[2];
    float* out = (float*)d_out;

    const int BC = in_sizes[0] / (LDIM * DDIM);  // B*C = 16
    const int C  = 8;

    dim3 grid(LDIM / 64, LDIM / 64, BC);   // (4, 4, 16) = 256 blocks = 1/CU
    dim3 block(16, 16);                    // 256 threads, 4 waves
    span_tanh_dot_kernel<<<grid, block, 0, stream>>>(start_h, end_h, v, out, C);
}

// Round 4
// 19.682 us; speedup vs baseline: 1.2075x; 1.2075x over previous
//
#include <hip/hip_runtime.h>

// out[b,i,j,c] = sum_d tanh(start[b,c,i,d] + end[b,c,j,d]) * v[d]
// B=2, C=8, L=256, D=128.
//
// tanh(x) = 1 - 2/(e^{2x}+1);  e^{2(s+e)} = Es*Ee, Es=exp2(K*s), K=2*log2(e).
// Per d-quad, all 4 divisions merge into ONE rcp:
//   sum_d v_d/q_d = (n01*cd + n23*ab)/(ab*cd),  q_d = fma(Es,Ee,1)
// -> 14 full-rate VALU + 1 trans per 4 elements.
// out = sum(v) - 2 * sum_d v_d/q_d.
//
// R3 lesson: occupancy > LDS-byte savings. 32x32 tile keeps 1024 blocks
// (4 blocks/CU, 16 waves/CU = 4/SIMD) so ds_read latency and rcp stalls
// cross-hide between waves. LDS bank time is negligible at this shape.

#define LDIM 256
#define DDIM 128
#define DPAD 132   // row stride 132 words == 4 mod 32 -> e-rows tx/tx+8 2-way (free)

__global__ __launch_bounds__(256) void span_tanh_dot_kernel(
    const float* __restrict__ start_h,
    const float* __restrict__ end_h,
    const float* __restrict__ v,
    float* __restrict__ out,
    int C)
{
    __shared__ float s_t[32][DPAD];
    __shared__ float e_t[32][DPAD];
    __shared__ float s_vsum;

    const int bc = blockIdx.z;            // b*C + c
    const int i0 = blockIdx.y * 32;
    const int j0 = blockIdx.x * 32;
    const int tx = threadIdx.x;           // 0..15
    const int ty = threadIdx.y;           // 0..15
    const int tid = ty * 16 + tx;

    const float K = 2.8853900817779268f;  // 2*log2(e)

    const float* sg = start_h + ((size_t)bc * LDIM + i0) * DDIM;
    const float* eg = end_h   + ((size_t)bc * LDIM + j0) * DDIM;

    // stage 32x128 tiles of Es=exp2(K*s), Ee=exp2(K*e); 4 float4 per thread per tensor.
    #pragma unroll
    for (int k = 0; k < 4; ++k) {
        const int idx = tid + k * 256;
        const int r  = idx >> 5;
        const int c4 = (idx & 31) << 2;
        float4 a = *(const float4*)(sg + r * DDIM + c4);
        a.x = __builtin_amdgcn_exp2f(K * a.x);
        a.y = __builtin_amdgcn_exp2f(K * a.y);
        a.z = __builtin_amdgcn_exp2f(K * a.z);
        a.w = __builtin_amdgcn_exp2f(K * a.w);
        *(float4*)(&s_t[r][c4]) = a;
        float4 b = *(const float4*)(eg + r * DDIM + c4);
        b.x = __builtin_amdgcn_exp2f(K * b.x);
        b.y = __builtin_amdgcn_exp2f(K * b.y);
        b.z = __builtin_amdgcn_exp2f(K * b.z);
        b.w = __builtin_amdgcn_exp2f(K * b.w);
        *(float4*)(&e_t[r][c4]) = b;
    }

    // sum(v): wave 0 reduces 128 floats
    if (tid < 64) {
        float2 vv = *(const float2*)(v + 2 * tid);
        float p = vv.x + vv.y;
        #pragma unroll
        for (int off = 32; off > 0; off >>= 1) p += __shfl_down(p, off);
        if (tid == 0) s_vsum = p;
    }
    __syncthreads();

    // 2x2 register blocking: rows {ty, ty+16}, cols {tx, tx+16}
    float acc00 = 0.f, acc01 = 0.f, acc10 = 0.f, acc11 = 0.f;

#define QUAD(ACC, S, E)                                            \
    {                                                              \
        float q0 = fmaf((S).x, (E).x, 1.0f);                       \
        float q1 = fmaf((S).y, (E).y, 1.0f);                       \
        float q2 = fmaf((S).z, (E).z, 1.0f);                       \
        float q3 = fmaf((S).w, (E).w, 1.0f);                       \
        float ab = q0 * q1, cd = q2 * q3;                          \
        float n01 = fmaf(v0, q1, v1 * q0);                         \
        float n23 = fmaf(v2, q3, v3 * q2);                         \
        float N = fmaf(n01, cd, n23 * ab);                         \
        float r = __builtin_amdgcn_rcpf(ab * cd);                  \
        ACC = fmaf(N, r, ACC);                                     \
    }

    #pragma unroll 4
    for (int d = 0; d < DDIM; d += 4) {
        const float4 sa = *(const float4*)(&s_t[ty     ][d]);  // 4 addr/wave, broadcast
        const float4 sb = *(const float4*)(&s_t[ty + 16][d]);
        const float4 ea = *(const float4*)(&e_t[tx     ][d]);  // 16 addr, 2-way: free
        const float4 eb = *(const float4*)(&e_t[tx + 16][d]);
        const float v0 = v[d], v1 = v[d + 1], v2 = v[d + 2], v3 = v[d + 3];

        QUAD(acc00, sa, ea);
        QUAD(acc01, sa, eb);
        QUAD(acc10, sb, ea);
        QUAD(acc11, sb, eb);
    }
#undef QUAD

    const int b_ = bc / C;
    const int c_ = bc - b_ * C;
    const float Sv = s_vsum;
    const int ia = i0 + ty, ib = i0 + ty + 16;
    const int ja = j0 + tx, jb = j0 + tx + 16;
    const size_t base = ((size_t)b_ * LDIM) * LDIM * C + c_;

    out[base + ((size_t)ia * LDIM + ja) * C] = fmaf(-2.f, acc00, Sv);
    out[base + ((size_t)ia * LDIM + jb) * C] = fmaf(-2.f, acc01, Sv);
    out[base + ((size_t)ib * LDIM + ja) * C] = fmaf(-2.f, acc10, Sv);
    out[base + ((size_t)ib * LDIM + jb) * C] = fmaf(-2.f, acc11, Sv);
}

extern "C" void kernel_launch(void* const* d_in, const int* in_sizes, int n_in,
                              void* d_out, int out_size, void* d_ws, size_t ws_size,
                              hipStream_t stream) {
    const float* start_h = (const float*)d_in[0];
    const float* end_h   = (const float*)d_in[1];
    const float* v       = (const float*)d_in[2];
    float* out = (float*)d_out;

    const int BC = in_sizes[0] / (LDIM * DDIM);  // B*C = 16
    const int C  = 8;

    dim3 grid(LDIM / 32, LDIM / 32, BC);   // (8, 8, 16) = 1024 blocks, 4/CU
    dim3 block(16, 16);                    // 256 threads, 4 waves
    span_tanh_dot_kernel<<<grid, block, 0, stream>>>(start_h, end_h, v, out, C);
}